// Round 16
// baseline (116.813 us; speedup 1.0000x reference)
//
#include <hip/hip_runtime.h>
#include <hip/hip_bf16.h>

#define B_   16
#define CIN  256
#define COUT 256
#define HH   64
#define WW   64
#define WDIM 512
#define OH   128
#define OW   128

typedef __attribute__((ext_vector_type(8))) short short8;
typedef __attribute__((ext_vector_type(4))) float f32x4;

__device__ __forceinline__ unsigned short f2bf(float f) {
    __hip_bfloat16 h = __float2bfloat16(f);
    return *reinterpret_cast<unsigned short*>(&h);
}
__device__ __forceinline__ float bf2f(unsigned short u) {
    unsigned int t = ((unsigned int)u) << 16;
    return *reinterpret_cast<float*>(&t);
}

// ws layout: bytes [0..16640) float scratch (sumsq partials + styles)
//            byte 32768:  wb bf16 [16][256 o][256 i]        (2 MB)
//            byte 4 MiB:  y  bf16 [16][256 o][64][64]       (33.5 MB)

__global__ __launch_bounds__(256) void k_styles(const float* __restrict__ w,
                                                const float* __restrict__ aw,
                                                const float* __restrict__ ab,
                                                float* __restrict__ ws) {
    int b = blockIdx.x, i = threadIdx.x;
    const float4* wr = (const float4*)(w + b * WDIM);
    const float4* ar = (const float4*)(aw + (size_t)i * WDIM);
    float acc = 0.f;
    #pragma unroll 4
    for (int k = 0; k < WDIM / 4; ++k) {
        float4 wv = wr[k], av = ar[k];
        acc += wv.x * av.x + wv.y * av.y + wv.z * av.z + wv.w * av.w;
    }
    const float wg = 0.04419417382415922f; // 1/sqrt(512)
    float st = acc * wg + ab[i];
    ws[64 + b * CIN + i] = st;
    __shared__ float sred[256];
    sred[i] = st * st;
    __syncthreads();
    for (int s = 128; s > 0; s >>= 1) {
        if (i < s) sred[i] += sred[i + s];
        __syncthreads();
    }
    if (i == 0) ws[b] = sred[0];
}

__global__ __launch_bounds__(64) void k_wb(const float* __restrict__ weight,
                                           const float* __restrict__ ws,
                                           unsigned short* __restrict__ wb) {
    int o = blockIdx.x, b = blockIdx.y, l = threadIdx.x;
    float tot = 0.f;
    #pragma unroll
    for (int j = 0; j < B_; ++j) tot += ws[j];
    float srs = rsqrtf(tot / (float)(B_ * CIN));
    float4 wk = *(const float4*)(weight + (size_t)o * CIN + l * 4);
    float ss = wk.x * wk.x + wk.y * wk.y + wk.z * wk.z + wk.w * wk.w;
    #pragma unroll
    for (int off = 32; off; off >>= 1) ss += __shfl_xor(ss, off);
    float wkn = rsqrtf(ss / (float)CIN);
    float4 st = *(const float4*)(ws + 64 + b * CIN + l * 4);
    float4 t;
    t.x = wk.x * wkn * st.x * srs;
    t.y = wk.y * wkn * st.y * srs;
    t.z = wk.z * wkn * st.z * srs;
    t.w = wk.w * wkn * st.w * srs;
    float s2 = t.x * t.x + t.y * t.y + t.z * t.z + t.w * t.w;
    #pragma unroll
    for (int off = 32; off; off >>= 1) s2 += __shfl_xor(s2, off);
    float dcoef = rsqrtf(s2 + 1e-8f);
    ushort4 pk;
    pk.x = f2bf(t.x * dcoef);
    pk.y = f2bf(t.y * dcoef);
    pk.z = f2bf(t.z * dcoef);
    pk.w = f2bf(t.w * dcoef);
    *(ushort4*)(wb + ((size_t)b * COUT + o) * CIN + l * 4) = pk;
}

// Conv5s: R8's verified conv5 body + XCD batch-affinity swizzle ONLY
// (normal cached loads/stores — R9's regression came from its nt y-stores).
// id&7 pins each XCD to 2 batches -> wb working set 256KB/XCD stays
// L2-resident under the x stream.
__global__ __launch_bounds__(512, 4) void k_conv5s(const float* __restrict__ x,
                                                   const float* __restrict__ bias,
                                                   const unsigned short* __restrict__ wb,
                                                   unsigned short* __restrict__ y) {
    __shared__ __align__(16) unsigned short xt[128 * CIN]; // 65536 B
    const int id = blockIdx.x;              // 0..511
    const int xcd = id & 7;
    const int j2 = id >> 3;                 // 0..63
    const int b = xcd + 8 * (j2 & 1);
    const int r2 = (j2 >> 1) * 2;           // first of 2 input rows
    const int tid = threadIdx.x;
    const int lane = tid & 63;
    const int wv = tid >> 6;
    const int lo = lane & 15, hi = lane >> 4;

    const unsigned short* wbb = wb + (size_t)b * COUT * CIN;
    short8 breg[2][8];
    #pragma unroll
    for (int c = 0; c < 2; ++c) {
        const int m0 = (wv * 2 + c) * 16;
        const unsigned short* wrow = wbb + (size_t)(m0 + lo) * CIN + hi * 8;
        #pragma unroll
        for (int ks = 0; ks < 8; ++ks)
            breg[c][ks] = *(const short8*)(wrow + ks * 32);
    }

    {
        const int c4 = tid & 15;
        const int rowsel = (tid >> 4) & 1;
        const int ig = tid >> 5;
        const float* xp = x + (size_t)b * CIN * (HH * WW) + (size_t)(r2 + rowsel) * WW + c4 * 4;
        const int pxbase = rowsel * 64 + c4 * 4;
        #pragma unroll
        for (int p = 0; p < 8; ++p) {
            const int i0 = ig * 16 + p * 2;
            float4 v0 = *(const float4*)(xp + (size_t)i0 * (HH * WW));
            float4 v1 = *(const float4*)(xp + (size_t)(i0 + 1) * (HH * WW));
            const int ib = i0 >> 3, e = i0 & 7;
            #pragma unroll
            for (int j = 0; j < 4; ++j) {
                const int px = pxbase + j;
                float f0 = (j == 0) ? v0.x : (j == 1) ? v0.y : (j == 2) ? v0.z : v0.w;
                float f1 = (j == 0) ? v1.x : (j == 1) ? v1.y : (j == 2) ? v1.z : v1.w;
                unsigned int pk = (unsigned int)f2bf(f0) | ((unsigned int)f2bf(f1) << 16);
                const int swz = ib ^ (px & 31) ^ ((px >> 2) & 7);
                *(unsigned int*)&xt[px * 256 + (swz << 3) + e] = pk;
            }
        }
    }
    __syncthreads();

    unsigned short* yb = y + (size_t)b * COUT * (HH * WW);

    #pragma unroll
    for (int c = 0; c < 2; ++c) {
        const int m0 = (wv * 2 + c) * 16;
        const float bs = bias[m0 + lo];
        unsigned short* yrow = yb + (size_t)(m0 + lo) * (HH * WW);
        #pragma unroll
        for (int g = 0; g < 8; ++g) {
            f32x4 acc = {0.f, 0.f, 0.f, 0.f};
            #pragma unroll
            for (int ks = 0; ks < 8; ++ks) {
                const int px = g * 16 + lo;
                const int ib = ks * 4 + hi;
                const int swz = ib ^ (px & 31) ^ ((px >> 2) & 7);
                short8 a = *(const short8*)&xt[px * 256 + (swz << 3)];
                acc = __builtin_amdgcn_mfma_f32_16x16x32_bf16(a, breg[c][ks], acc, 0, 0, 0);
            }
            ushort4 pk;
            pk.x = f2bf(acc[0] + bs);
            pk.y = f2bf(acc[1] + bs);
            pk.z = f2bf(acc[2] + bs);
            pk.w = f2bf(acc[3] + bs);
            const int prow = g >> 2;
            const int pcol = (g & 3) * 16 + hi * 4;
            *(ushort4*)(yrow + (size_t)(r2 + prow) * WW + pcol) = pk;
        }
    }
}

// Upsample — verbatim R8 (verified best): half-wave per (b, ch, p), reads y
// rows p-1,p,p+1 (cache-hot), writes out rows 2p, 2p+1. 8 blocks/CU.
__global__ __launch_bounds__(256, 8) void k_up(const unsigned short* __restrict__ y,
                                               float* __restrict__ out) {
    const int tid = threadIdx.x;
    const int t = tid & 31;
    const int s = tid >> 5;
    const int idx = blockIdx.x * 8 + s;
    const int p = idx & 63;
    const int ch = (idx >> 6) & 255;
    const int b = idx >> 14;

    const unsigned short* yb = y + (size_t)(b * COUT + ch) * (HH * WW);
    const int pm1 = max(p - 1, 0), pp1 = min(p + 1, HH - 1);
    unsigned int T  = *(const unsigned int*)(yb + pm1 * WW + 2 * t);
    unsigned int M  = *(const unsigned int*)(yb + p   * WW + 2 * t);
    unsigned int Bt = *(const unsigned int*)(yb + pp1 * WW + 2 * t);

    float tB = bf2f((unsigned short)(T & 0xffff)),  tC = bf2f((unsigned short)(T >> 16));
    float mB = bf2f((unsigned short)(M & 0xffff)),  mC = bf2f((unsigned short)(M >> 16));
    float bB = bf2f((unsigned short)(Bt & 0xffff)), bC = bf2f((unsigned short)(Bt >> 16));

    float aB = 0.25f * tB + 0.75f * mB, aC = 0.25f * tC + 0.75f * mC;
    float eB = 0.75f * mB + 0.25f * bB, eC = 0.75f * mC + 0.25f * bC;

    float aA = __shfl_up(aC, 1, 32);   if (t == 0)  aA = aB;
    float aD = __shfl_down(aB, 1, 32); if (t == 31) aD = aC;
    float eA = __shfl_up(eC, 1, 32);   if (t == 0)  eA = eB;
    float eD = __shfl_down(eB, 1, 32); if (t == 31) eD = eC;

    float4 o0, o1;
    o0.x = 0.25f * aA + 0.75f * aB;
    o0.y = 0.75f * aB + 0.25f * aC;
    o0.z = 0.25f * aB + 0.75f * aC;
    o0.w = 0.75f * aC + 0.25f * aD;
    o1.x = 0.25f * eA + 0.75f * eB;
    o1.y = 0.75f * eB + 0.25f * eC;
    o1.z = 0.25f * eB + 0.75f * eC;
    o1.w = 0.75f * eC + 0.25f * eD;

    float* op = out + (size_t)(b * COUT + ch) * (OH * OW) + (2 * p) * OW + 4 * t;
    *(float4*)op = o0;
    *(float4*)(op + OW) = o1;
}

extern "C" void kernel_launch(void* const* d_in, const int* in_sizes, int n_in,
                              void* d_out, int out_size, void* d_ws, size_t ws_size,
                              hipStream_t stream) {
    (void)in_sizes; (void)n_in; (void)out_size; (void)ws_size;
    const float* x      = (const float*)d_in[0];
    const float* w      = (const float*)d_in[1];
    const float* aw     = (const float*)d_in[2];
    const float* ab     = (const float*)d_in[3];
    const float* weight = (const float*)d_in[4];
    const float* bias   = (const float*)d_in[5];
    float* out = (float*)d_out;
    float* wsf = (float*)d_ws;
    unsigned short* wb = (unsigned short*)((char*)d_ws + 32768);
    unsigned short* y  = (unsigned short*)((char*)d_ws + (4u << 20));

    hipLaunchKernelGGL(k_styles, dim3(16), dim3(256), 0, stream, w, aw, ab, wsf);
    hipLaunchKernelGGL(k_wb, dim3(COUT, B_), dim3(64), 0, stream, weight, wsf, wb);
    hipLaunchKernelGGL(k_conv5s, dim3(HH / 2 * B_), dim3(512), 0, stream, x, bias, wb, y);
    hipLaunchKernelGGL(k_up, dim3(B_ * COUT * HH / 8), dim3(256), 0, stream, y, out);
}

// Round 17
// 110.565 us; speedup vs baseline: 1.0565x; 1.0565x over previous
//
#include <hip/hip_runtime.h>
#include <hip/hip_bf16.h>

#define B_   16
#define CIN  256
#define COUT 256
#define HH   64
#define WW   64
#define WDIM 512
#define OH   128
#define OW   128

typedef __attribute__((ext_vector_type(8))) short short8;
typedef __attribute__((ext_vector_type(4))) float f32x4;

__device__ __forceinline__ unsigned short f2bf(float f) {
    __hip_bfloat16 h = __float2bfloat16(f);
    return *reinterpret_cast<unsigned short*>(&h);
}
__device__ __forceinline__ float bf2f(unsigned short u) {
    unsigned int t = ((unsigned int)u) << 16;
    return *reinterpret_cast<float*>(&t);
}

// ws layout: bytes [0..16640) float scratch (sumsq partials + styles)
//            byte 32768:  wb bf16 [16][256 o][256 i]        (2 MB)
//            byte 4 MiB:  y  bf16 [16][256 o][64][64]       (33.5 MB)

__global__ __launch_bounds__(256) void k_styles(const float* __restrict__ w,
                                                const float* __restrict__ aw,
                                                const float* __restrict__ ab,
                                                float* __restrict__ ws) {
    int b = blockIdx.x, i = threadIdx.x;
    const float4* wr = (const float4*)(w + b * WDIM);
    const float4* ar = (const float4*)(aw + (size_t)i * WDIM);
    float acc = 0.f;
    #pragma unroll 4
    for (int k = 0; k < WDIM / 4; ++k) {
        float4 wv = wr[k], av = ar[k];
        acc += wv.x * av.x + wv.y * av.y + wv.z * av.z + wv.w * av.w;
    }
    const float wg = 0.04419417382415922f; // 1/sqrt(512)
    float st = acc * wg + ab[i];
    ws[64 + b * CIN + i] = st;
    __shared__ float sred[256];
    sred[i] = st * st;
    __syncthreads();
    for (int s = 128; s > 0; s >>= 1) {
        if (i < s) sred[i] += sred[i + s];
        __syncthreads();
    }
    if (i == 0) ws[b] = sred[0];
}

__global__ __launch_bounds__(64) void k_wb(const float* __restrict__ weight,
                                           const float* __restrict__ ws,
                                           unsigned short* __restrict__ wb) {
    int o = blockIdx.x, b = blockIdx.y, l = threadIdx.x;
    float tot = 0.f;
    #pragma unroll
    for (int j = 0; j < B_; ++j) tot += ws[j];
    float srs = rsqrtf(tot / (float)(B_ * CIN));
    float4 wk = *(const float4*)(weight + (size_t)o * CIN + l * 4);
    float ss = wk.x * wk.x + wk.y * wk.y + wk.z * wk.z + wk.w * wk.w;
    #pragma unroll
    for (int off = 32; off; off >>= 1) ss += __shfl_xor(ss, off);
    float wkn = rsqrtf(ss / (float)CIN);
    float4 st = *(const float4*)(ws + 64 + b * CIN + l * 4);
    float4 t;
    t.x = wk.x * wkn * st.x * srs;
    t.y = wk.y * wkn * st.y * srs;
    t.z = wk.z * wkn * st.z * srs;
    t.w = wk.w * wkn * st.w * srs;
    float s2 = t.x * t.x + t.y * t.y + t.z * t.z + t.w * t.w;
    #pragma unroll
    for (int off = 32; off; off >>= 1) s2 += __shfl_xor(s2, off);
    float dcoef = rsqrtf(s2 + 1e-8f);
    ushort4 pk;
    pk.x = f2bf(t.x * dcoef);
    pk.y = f2bf(t.y * dcoef);
    pk.z = f2bf(t.z * dcoef);
    pk.w = f2bf(t.w * dcoef);
    *(ushort4*)(wb + ((size_t)b * COUT + o) * CIN + l * 4) = pk;
}

// Conv5 — verified best (R8/R15). Block = 2 rows x 64 cols, 512 thr,
// waves split o (wb loaded once per wave), 1 barrier, direct ushort4 y stores.
__global__ __launch_bounds__(512, 4) void k_conv5(const float* __restrict__ x,
                                                  const float* __restrict__ bias,
                                                  const unsigned short* __restrict__ wb,
                                                  unsigned short* __restrict__ y) {
    __shared__ __align__(16) unsigned short xt[128 * CIN]; // 65536 B
    const int r2 = blockIdx.x * 2;
    const int b = blockIdx.y;
    const int tid = threadIdx.x;
    const int lane = tid & 63;
    const int wv = tid >> 6;
    const int lo = lane & 15, hi = lane >> 4;

    const unsigned short* wbb = wb + (size_t)b * COUT * CIN;
    short8 breg[2][8];
    #pragma unroll
    for (int c = 0; c < 2; ++c) {
        const int m0 = (wv * 2 + c) * 16;
        const unsigned short* wrow = wbb + (size_t)(m0 + lo) * CIN + hi * 8;
        #pragma unroll
        for (int ks = 0; ks < 8; ++ks)
            breg[c][ks] = *(const short8*)(wrow + ks * 32);
    }

    {
        const int c4 = tid & 15;
        const int rowsel = (tid >> 4) & 1;
        const int ig = tid >> 5;
        const float* xp = x + (size_t)b * CIN * (HH * WW) + (size_t)(r2 + rowsel) * WW + c4 * 4;
        const int pxbase = rowsel * 64 + c4 * 4;
        #pragma unroll
        for (int p = 0; p < 8; ++p) {
            const int i0 = ig * 16 + p * 2;
            float4 v0 = *(const float4*)(xp + (size_t)i0 * (HH * WW));
            float4 v1 = *(const float4*)(xp + (size_t)(i0 + 1) * (HH * WW));
            const int ib = i0 >> 3, e = i0 & 7;
            #pragma unroll
            for (int j = 0; j < 4; ++j) {
                const int px = pxbase + j;
                float f0 = (j == 0) ? v0.x : (j == 1) ? v0.y : (j == 2) ? v0.z : v0.w;
                float f1 = (j == 0) ? v1.x : (j == 1) ? v1.y : (j == 2) ? v1.z : v1.w;
                unsigned int pk = (unsigned int)f2bf(f0) | ((unsigned int)f2bf(f1) << 16);
                const int swz = ib ^ (px & 31) ^ ((px >> 2) & 7);
                *(unsigned int*)&xt[px * 256 + (swz << 3) + e] = pk;
            }
        }
    }
    __syncthreads();

    unsigned short* yb = y + (size_t)b * COUT * (HH * WW);

    #pragma unroll
    for (int c = 0; c < 2; ++c) {
        const int m0 = (wv * 2 + c) * 16;
        const float bs = bias[m0 + lo];
        unsigned short* yrow = yb + (size_t)(m0 + lo) * (HH * WW);
        #pragma unroll
        for (int g = 0; g < 8; ++g) {
            f32x4 acc = {0.f, 0.f, 0.f, 0.f};
            #pragma unroll
            for (int ks = 0; ks < 8; ++ks) {
                const int px = g * 16 + lo;
                const int ib = ks * 4 + hi;
                const int swz = ib ^ (px & 31) ^ ((px >> 2) & 7);
                short8 a = *(const short8*)&xt[px * 256 + (swz << 3)];
                acc = __builtin_amdgcn_mfma_f32_16x16x32_bf16(a, breg[c][ks], acc, 0, 0, 0);
            }
            ushort4 pk;
            pk.x = f2bf(acc[0] + bs);
            pk.y = f2bf(acc[1] + bs);
            pk.z = f2bf(acc[2] + bs);
            pk.w = f2bf(acc[3] + bs);
            const int prow = g >> 2;
            const int pcol = (g & 3) * 16 + hi * 4;
            *(ushort4*)(yrow + (size_t)(r2 + prow) * WW + pcol) = pk;
        }
    }
}

// k_up2 — verified best (R15): one block per (b,ch), stage the 8KB y channel
// image into LDS once (coalesced uint4), each half-wave emits full 512B
// output rows.
#define YP 72   // padded u16 stride
__global__ __launch_bounds__(256, 4) void k_up2(const unsigned short* __restrict__ y,
                                                float* __restrict__ out) {
    __shared__ __align__(16) unsigned short ylds[HH * YP]; // 9216 B
    const int id = blockIdx.x;          // b*COUT + ch
    const int tid = threadIdx.x;

    {
        const uint4* src = (const uint4*)(y + (size_t)id * (HH * WW));
        uint4 v0 = src[tid * 2];
        uint4 v1 = src[tid * 2 + 1];
        const int row = tid >> 2;
        const int cu = (tid & 3) * 16;
        *(uint4*)&ylds[row * YP + cu] = v0;
        *(uint4*)&ylds[row * YP + cu + 8] = v1;
    }
    __syncthreads();

    const int t = tid & 31;
    const int oru = tid >> 5;
    const int c0 = max(2 * t - 1, 0);
    const int c1 = 2 * t;
    const int c2 = 2 * t + 1;
    const int c3 = min(2 * t + 2, WW - 1);
    float* ob = out + (size_t)id * (OH * OW);

    #pragma unroll
    for (int i = 0; i < 16; ++i) {
        const int orow = oru * 16 + i;
        const int raw = (orow - 1) >> 1;
        const int yr0 = max(raw, 0);
        const int yr1 = min(raw + 1, HH - 1);
        const float wr0 = (orow & 1) ? 0.75f : 0.25f;
        const float wr1 = 1.f - wr0;
        const unsigned short* R0 = &ylds[yr0 * YP];
        const unsigned short* R1 = &ylds[yr1 * YP];
        float vA = wr0 * bf2f(R0[c0]) + wr1 * bf2f(R1[c0]);
        float vB = wr0 * bf2f(R0[c1]) + wr1 * bf2f(R1[c1]);
        float vC = wr0 * bf2f(R0[c2]) + wr1 * bf2f(R1[c2]);
        float vD = wr0 * bf2f(R0[c3]) + wr1 * bf2f(R1[c3]);
        float4 ov;
        ov.x = 0.25f * vA + 0.75f * vB;
        ov.y = 0.75f * vB + 0.25f * vC;
        ov.z = 0.25f * vB + 0.75f * vC;
        ov.w = 0.75f * vC + 0.25f * vD;
        *(float4*)(ob + (size_t)orow * OW + 4 * t) = ov;
    }
}

extern "C" void kernel_launch(void* const* d_in, const int* in_sizes, int n_in,
                              void* d_out, int out_size, void* d_ws, size_t ws_size,
                              hipStream_t stream) {
    (void)in_sizes; (void)n_in; (void)out_size; (void)ws_size;
    const float* x      = (const float*)d_in[0];
    const float* w      = (const float*)d_in[1];
    const float* aw     = (const float*)d_in[2];
    const float* ab     = (const float*)d_in[3];
    const float* weight = (const float*)d_in[4];
    const float* bias   = (const float*)d_in[5];
    float* out = (float*)d_out;
    float* wsf = (float*)d_ws;
    unsigned short* wb = (unsigned short*)((char*)d_ws + 32768);
    unsigned short* y  = (unsigned short*)((char*)d_ws + (4u << 20));

    hipLaunchKernelGGL(k_styles, dim3(16), dim3(256), 0, stream, w, aw, ab, wsf);
    hipLaunchKernelGGL(k_wb, dim3(COUT, B_), dim3(64), 0, stream, weight, wsf, wb);
    hipLaunchKernelGGL(k_conv5, dim3(HH / 2, B_), dim3(512), 0, stream, x, bias, wb, y);
    hipLaunchKernelGGL(k_up2, dim3(B_ * COUT), dim3(256), 0, stream, y, out);
}